// Round 6
// baseline (36.759 us; speedup 1.0000x reference)
//
#include <hip/hip_runtime.h>
#include <hip/hip_bf16.h>
#include <math.h>

#define BB 8
#define SS 2048
#define HH 768
#define NN 512
#define MAXW 30
#define SPW 8            // spans (waves) per block
#define CH  8            // tokens per chunk

// ---- Kernel A: per-example counting sort of spans by start (parallel scan) ----
__global__ __launch_bounds__(256) void sort_spans_kernel(
    const int* __restrict__ starts,   // (B, N)
    int*       __restrict__ order)    // (B, N): order[b*N + rank] = span idx
{
    const int b   = blockIdx.x;
    const int tid = threadIdx.x;
    __shared__ int hist[SS];
    __shared__ int wsum[4];

    for (int i = tid; i < SS; i += 256) hist[i] = 0;
    __syncthreads();

    const int* st = starts + b * NN;
    for (int n = tid; n < NN; n += 256) atomicAdd(&hist[st[n]], 1);
    __syncthreads();

    const int base = tid * 8;
    int cnt[8]; int s = 0;
    #pragma unroll
    for (int k = 0; k < 8; ++k) { cnt[k] = hist[base + k]; s += cnt[k]; }

    const int lane = tid & 63, wv = tid >> 6;
    int v = s;
    #pragma unroll
    for (int off = 1; off < 64; off <<= 1) {
        int u = __shfl_up(v, off);
        if (lane >= off) v += u;
    }
    if (lane == 63) wsum[wv] = v;
    __syncthreads();
    int wbase = 0;
    #pragma unroll
    for (int k = 0; k < 4; ++k) wbase += (k < wv) ? wsum[k] : 0;

    int excl = wbase + v - s;
    #pragma unroll
    for (int k = 0; k < 8; ++k) { int c = cnt[k]; hist[base + k] = excl; excl += c; }
    __syncthreads();

    for (int n = tid; n < NN; n += 256) {
        int pos = atomicAdd(&hist[st[n]], 1);
        order[b * NN + pos] = n;
    }
}

// ---- Kernel B: 8 consecutive sorted spans per block (one wave each).
//      Token-major sweep over the union window; each row loaded from global
//      ONCE per block, scored once, then consumed from LDS by covering waves.
__global__ __launch_bounds__(512, 4) void span_block_kernel(
    const float* __restrict__ emb,      // (B, S, H)
    const float* __restrict__ w,        // (H)
    const float* __restrict__ bias,     // (1)
    const int*   __restrict__ starts,   // (B, N)
    const int*   __restrict__ lengths,  // (B, N)
    const int*   __restrict__ order,    // (B, N) or nullptr
    float*       __restrict__ out)      // (B, N, 3H)
{
    const int tid  = threadIdx.x;
    const int wv   = tid >> 6;
    const int lane = tid & 63;
    const int bi   = blockIdx.x & 7;                 // example <-> XCD
    const int g    = (int)blockIdx.x >> 3;
    const int rank = g * SPW + wv;
    const int n    = order ? order[bi * NN + rank] : rank;
    const int span = bi * NN + n;

    const int start = starts[span];
    const int len   = lengths[span];                 // valid t = start..start+len
    const int end   = start + len;

    __shared__ float s_rows[2][CH][HH];              // 48 KiB
    __shared__ float s_scr[2][CH];
    __shared__ int   s_s[SPW], s_e[SPW];

    if (lane == 0) { s_s[wv] = start; s_e[wv] = end; }
    __syncthreads();
    int wlo = s_s[0], whi = s_e[0];
    #pragma unroll
    for (int k = 1; k < SPW; ++k) { wlo = min(wlo, s_s[k]); whi = max(whi, s_e[k]); }

    const int h0 = lane * 4;
    const float* ebase = emb + (size_t)bi * SS * HH;
    const float4 w0 = *reinterpret_cast<const float4*>(w + h0);
    const float4 w1 = *reinterpret_cast<const float4*>(w + h0 + 256);
    const float4 w2 = *reinterpret_cast<const float4*>(w + h0 + 512);
    const float bb = bias[0];

    const int nch = (whi - wlo) / CH + 1;            // ceil(window / CH)

    // producer: wave wv loads token (wlo + c*CH + wv), scores it, stores to LDS
    auto produce = [&](int c) {
        const int tok = wlo + c * CH + wv;
        if (tok <= whi) {
            const float* rp = ebase + (size_t)tok * HH + h0;
            float4 v0 = *reinterpret_cast<const float4*>(rp);
            float4 v1 = *reinterpret_cast<const float4*>(rp + 256);
            float4 v2 = *reinterpret_cast<const float4*>(rp + 512);
            float d = v0.x * w0.x + v0.y * w0.y + v0.z * w0.z + v0.w * w0.w
                    + v1.x * w1.x + v1.y * w1.y + v1.z * w1.z + v1.w * w1.w
                    + v2.x * w2.x + v2.y * w2.y + v2.z * w2.z + v2.w * w2.w;
            #pragma unroll
            for (int off = 32; off; off >>= 1) d += __shfl_xor(d, off);
            float* dst = &s_rows[c & 1][wv][h0];
            *reinterpret_cast<float4*>(dst)       = v0;
            *reinterpret_cast<float4*>(dst + 256) = v1;
            *reinterpret_cast<float4*>(dst + 512) = v2;
            if (lane == 0) s_scr[c & 1][wv] = d + bb;
        }
    };

    float m = -INFINITY, ssum = 0.f;
    float4 a0 = make_float4(0.f, 0.f, 0.f, 0.f), a1 = a0, a2 = a0;
    float* orow = out + (size_t)span * (3 * HH);

    produce(0);
    __syncthreads();

    for (int c = 0; c < nch; ++c) {
        if (c + 1 < nch) produce(c + 1);             // prefetch next chunk

        const int clo = wlo + c * CH;
        const int t0  = max(clo, start);
        const int t1  = min(clo + CH - 1, end);
        const int buf = c & 1;

        if (t0 <= t1) {
            // 1-deep LDS preload pipeline
            int j = t0 - clo;
            float ds = s_scr[buf][j];
            const float* rp0 = &s_rows[buf][j][h0];
            float4 v0 = *reinterpret_cast<const float4*>(rp0);
            float4 v1 = *reinterpret_cast<const float4*>(rp0 + 256);
            float4 v2 = *reinterpret_cast<const float4*>(rp0 + 512);

            for (int t = t0; t <= t1; ++t) {
                float nds = 0.f; float4 n0, n1, n2;
                if (t < t1) {
                    const int j2 = t + 1 - clo;
                    nds = s_scr[buf][j2];
                    const float* np = &s_rows[buf][j2][h0];
                    n0 = *reinterpret_cast<const float4*>(np);
                    n1 = *reinterpret_cast<const float4*>(np + 256);
                    n2 = *reinterpret_cast<const float4*>(np + 512);
                }

                if (ds > m) {                        // wave-uniform
                    const float cc = __expf(m - ds); // first token: exp(-inf)=0
                    ssum *= cc;
                    a0.x *= cc; a0.y *= cc; a0.z *= cc; a0.w *= cc;
                    a1.x *= cc; a1.y *= cc; a1.z *= cc; a1.w *= cc;
                    a2.x *= cc; a2.y *= cc; a2.z *= cc; a2.w *= cc;
                    m = ds;
                }
                const float pt = __expf(ds - m);
                ssum += pt;
                a0.x += pt * v0.x; a0.y += pt * v0.y; a0.z += pt * v0.z; a0.w += pt * v0.w;
                a1.x += pt * v1.x; a1.y += pt * v1.y; a1.z += pt * v1.z; a1.w += pt * v1.w;
                a2.x += pt * v2.x; a2.y += pt * v2.y; a2.z += pt * v2.z; a2.w += pt * v2.w;

                if (t == start) {
                    *reinterpret_cast<float4*>(orow + h0)       = v0;
                    *reinterpret_cast<float4*>(orow + h0 + 256) = v1;
                    *reinterpret_cast<float4*>(orow + h0 + 512) = v2;
                }
                if (t == end) {
                    *reinterpret_cast<float4*>(orow + HH + h0)       = v0;
                    *reinterpret_cast<float4*>(orow + HH + h0 + 256) = v1;
                    *reinterpret_cast<float4*>(orow + HH + h0 + 512) = v2;
                }

                ds = nds; v0 = n0; v1 = n1; v2 = n2;
            }
        }
        __syncthreads();
    }

    const float inv = 1.f / ssum;
    a0.x *= inv; a0.y *= inv; a0.z *= inv; a0.w *= inv;
    a1.x *= inv; a1.y *= inv; a1.z *= inv; a1.w *= inv;
    a2.x *= inv; a2.y *= inv; a2.z *= inv; a2.w *= inv;
    *reinterpret_cast<float4*>(orow + 2 * HH + h0)       = a0;
    *reinterpret_cast<float4*>(orow + 2 * HH + h0 + 256) = a1;
    *reinterpret_cast<float4*>(orow + 2 * HH + h0 + 512) = a2;
}

extern "C" void kernel_launch(void* const* d_in, const int* in_sizes, int n_in,
                              void* d_out, int out_size, void* d_ws, size_t ws_size,
                              hipStream_t stream) {
    const float* emb     = (const float*)d_in[0];
    const float* w       = (const float*)d_in[1];
    const float* bias    = (const float*)d_in[2];
    const int*   starts  = (const int*)d_in[3];
    const int*   lengths = (const int*)d_in[4];
    float*       out     = (float*)d_out;

    int* order = nullptr;
    if (ws_size >= (size_t)(BB * NN * sizeof(int))) {
        order = (int*)d_ws;
        sort_spans_kernel<<<dim3(BB), dim3(256), 0, stream>>>(starts, order);
    }

    span_block_kernel<<<dim3(BB * NN / SPW), dim3(512), 0, stream>>>(
        emb, w, bias, starts, lengths, order, out);
}

// Round 7
// 33.192 us; speedup vs baseline: 1.1075x; 1.1075x over previous
//
#include <hip/hip_runtime.h>
#include <hip/hip_bf16.h>
#include <math.h>

#define BB 8
#define SS 2048
#define HH 768
#define NN 512
#define MAXW 30

// ---- Kernel A: per-example counting sort of spans by start (parallel scan) ----
__global__ __launch_bounds__(256) void sort_spans_kernel(
    const int* __restrict__ starts,   // (B, N)
    int*       __restrict__ order)    // (B, N): order[b*N + rank] = span idx
{
    const int b   = blockIdx.x;
    const int tid = threadIdx.x;
    __shared__ int hist[SS];
    __shared__ int wsum[4];

    for (int i = tid; i < SS; i += 256) hist[i] = 0;
    __syncthreads();

    const int* st = starts + b * NN;
    for (int n = tid; n < NN; n += 256) atomicAdd(&hist[st[n]], 1);
    __syncthreads();

    const int base = tid * 8;
    int cnt[8]; int s = 0;
    #pragma unroll
    for (int k = 0; k < 8; ++k) { cnt[k] = hist[base + k]; s += cnt[k]; }

    const int lane = tid & 63, wv = tid >> 6;
    int v = s;
    #pragma unroll
    for (int off = 1; off < 64; off <<= 1) {
        int u = __shfl_up(v, off);
        if (lane >= off) v += u;
    }
    if (lane == 63) wsum[wv] = v;
    __syncthreads();
    int wbase = 0;
    #pragma unroll
    for (int k = 0; k < 4; ++k) wbase += (k < wv) ? wsum[k] : 0;

    int excl = wbase + v - s;
    #pragma unroll
    for (int k = 0; k < 8; ++k) { int c = cnt[k]; hist[base + k] = excl; excl += c; }
    __syncthreads();

    for (int n = tid; n < NN; n += 256) {
        int pos = atomicAdd(&hist[st[n]], 1);
        order[b * NN + pos] = n;
    }
}

// ---- Kernel B: 2 waves per span (each wave half the tokens), 2 spans per
//      256-thread block. Online softmax per half + LDS pair-merge.
__global__ __launch_bounds__(256, 6) void span_split_kernel(
    const float* __restrict__ emb,      // (B, S, H)
    const float* __restrict__ w,        // (H)
    const float* __restrict__ bias,     // (1)
    const int*   __restrict__ starts,   // (B, N)
    const int*   __restrict__ lengths,  // (B, N)
    const int*   __restrict__ order,    // (B, N) or nullptr
    float*       __restrict__ out)      // (B, N, 3H)
{
    const int tid  = threadIdx.x;
    const int wv   = tid >> 6;           // 0..3
    const int lane = tid & 63;
    const int p    = wv >> 1;            // pair (span slot) 0..1
    const int hf   = wv & 1;             // half 0..1

    const int bi   = blockIdx.x & 7;     // example <-> XCD
    const int g    = (int)blockIdx.x >> 3;       // 0..255 per example
    const int rank = g * 2 + p;
    const int n    = order ? order[bi * NN + rank] : rank;
    const int span = bi * NN + n;

    const int start = starts[span];
    const int len   = lengths[span];     // valid t = 0..len (<= 29)
    const int cntT  = len + 1;
    const int mid   = (cntT + 1) >> 1;   // wave0: [0, mid-1], wave1: [mid, len]
    const int t_lo  = hf ? mid : 0;
    const int t_hi  = hf ? len : (mid - 1);

    const float* ebase = emb + (size_t)bi * SS * HH + (size_t)start * HH;
    const int h0 = lane * 4;
    float* orow = out + (size_t)span * (3 * HH);

    const float4 w0 = *reinterpret_cast<const float4*>(w + h0);
    const float4 w1 = *reinterpret_cast<const float4*>(w + h0 + 256);
    const float4 w2 = *reinterpret_cast<const float4*>(w + h0 + 512);
    const float bb = bias[0];

    float m = -INFINITY, ssum = 0.f;
    float4 a0 = make_float4(0.f, 0.f, 0.f, 0.f), a1 = a0, a2 = a0;

    if (t_lo <= t_hi) {
        const float* row = ebase + (size_t)t_lo * HH;
        float4 v0 = *reinterpret_cast<const float4*>(row + h0);
        float4 v1 = *reinterpret_cast<const float4*>(row + h0 + 256);
        float4 v2 = *reinterpret_cast<const float4*>(row + h0 + 512);

        for (int t = t_lo; t <= t_hi; ++t) {
            float4 n0, n1, n2;
            if (t < t_hi) {
                const float* nr = row + HH;
                n0 = *reinterpret_cast<const float4*>(nr + h0);
                n1 = *reinterpret_cast<const float4*>(nr + h0 + 256);
                n2 = *reinterpret_cast<const float4*>(nr + h0 + 512);
            }

            float d = v0.x * w0.x + v0.y * w0.y + v0.z * w0.z + v0.w * w0.w
                    + v1.x * w1.x + v1.y * w1.y + v1.z * w1.z + v1.w * w1.w
                    + v2.x * w2.x + v2.y * w2.y + v2.z * w2.z + v2.w * w2.w;
            #pragma unroll
            for (int off = 32; off; off >>= 1) d += __shfl_xor(d, off);
            d += bb;

            if (d > m) {                 // wave-uniform
                const float c = __expf(m - d);   // first iter: exp(-inf)=0
                ssum *= c;
                a0.x *= c; a0.y *= c; a0.z *= c; a0.w *= c;
                a1.x *= c; a1.y *= c; a1.z *= c; a1.w *= c;
                a2.x *= c; a2.y *= c; a2.z *= c; a2.w *= c;
                m = d;
            }
            const float pt = __expf(d - m);
            ssum += pt;
            a0.x += pt * v0.x; a0.y += pt * v0.y; a0.z += pt * v0.z; a0.w += pt * v0.w;
            a1.x += pt * v1.x; a1.y += pt * v1.y; a1.z += pt * v1.z; a1.w += pt * v1.w;
            a2.x += pt * v2.x; a2.y += pt * v2.y; a2.z += pt * v2.z; a2.w += pt * v2.w;

            if (t == 0) {                // start row (wave 0 only, by range)
                *reinterpret_cast<float4*>(orow + h0)       = v0;
                *reinterpret_cast<float4*>(orow + h0 + 256) = v1;
                *reinterpret_cast<float4*>(orow + h0 + 512) = v2;
            }
            if (t == len) {              // end row (the wave whose range has len)
                *reinterpret_cast<float4*>(orow + HH + h0)       = v0;
                *reinterpret_cast<float4*>(orow + HH + h0 + 256) = v1;
                *reinterpret_cast<float4*>(orow + HH + h0 + 512) = v2;
            }

            v0 = n0; v1 = n1; v2 = n2;
            row += HH;
        }
    }

    // ---- pair merge: combine (m, ssum, acc) of the two halves ----
    __shared__ float s_m[2][2];          // [pair][half]
    __shared__ float s_sum[2][2];
    __shared__ float s_acc[2][HH];       // partner (half 1) scaled accumulator

    s_m[p][hf] = m;
    __syncthreads();
    const float M = fmaxf(s_m[p][0], s_m[p][1]);
    const float c = __expf(m - M);       // empty half: exp(-inf)=0
    ssum *= c;
    a0.x *= c; a0.y *= c; a0.z *= c; a0.w *= c;
    a1.x *= c; a1.y *= c; a1.z *= c; a1.w *= c;
    a2.x *= c; a2.y *= c; a2.z *= c; a2.w *= c;

    if (hf == 1) {
        s_sum[p][1] = ssum;              // lane 0..63 all write same value; benign
        float* dst = &s_acc[p][h0];
        *reinterpret_cast<float4*>(dst)       = a0;
        *reinterpret_cast<float4*>(dst + 256) = a1;
        *reinterpret_cast<float4*>(dst + 512) = a2;
    }
    __syncthreads();

    if (hf == 0) {
        const float total = ssum + s_sum[p][1];
        const float inv = 1.f / total;
        const float* src = &s_acc[p][h0];
        float4 b0 = *reinterpret_cast<const float4*>(src);
        float4 b1 = *reinterpret_cast<const float4*>(src + 256);
        float4 b2 = *reinterpret_cast<const float4*>(src + 512);
        a0.x = (a0.x + b0.x) * inv; a0.y = (a0.y + b0.y) * inv;
        a0.z = (a0.z + b0.z) * inv; a0.w = (a0.w + b0.w) * inv;
        a1.x = (a1.x + b1.x) * inv; a1.y = (a1.y + b1.y) * inv;
        a1.z = (a1.z + b1.z) * inv; a1.w = (a1.w + b1.w) * inv;
        a2.x = (a2.x + b2.x) * inv; a2.y = (a2.y + b2.y) * inv;
        a2.z = (a2.z + b2.z) * inv; a2.w = (a2.w + b2.w) * inv;
        *reinterpret_cast<float4*>(orow + 2 * HH + h0)       = a0;
        *reinterpret_cast<float4*>(orow + 2 * HH + h0 + 256) = a1;
        *reinterpret_cast<float4*>(orow + 2 * HH + h0 + 512) = a2;
    }
}

extern "C" void kernel_launch(void* const* d_in, const int* in_sizes, int n_in,
                              void* d_out, int out_size, void* d_ws, size_t ws_size,
                              hipStream_t stream) {
    const float* emb     = (const float*)d_in[0];
    const float* w       = (const float*)d_in[1];
    const float* bias    = (const float*)d_in[2];
    const int*   starts  = (const int*)d_in[3];
    const int*   lengths = (const int*)d_in[4];
    float*       out     = (float*)d_out;

    int* order = nullptr;
    if (ws_size >= (size_t)(BB * NN * sizeof(int))) {
        order = (int*)d_ws;
        sort_spans_kernel<<<dim3(BB), dim3(256), 0, stream>>>(starts, order);
    }

    // 2 waves per span, 2 spans per 256-thread block -> B*N/2 blocks
    span_split_kernel<<<dim3(BB * NN / 2), dim3(256), 0, stream>>>(
        emb, w, bias, starts, lengths, order, out);
}